// Round 1
// baseline (479.788 us; speedup 1.0000x reference)
//
#include <hip/hip_runtime.h>

#define N_NODES 50000
#define N_EDGES 800000
#define DIM 64
#define NEG_SLOPE 0.2f

// Order-preserving float->uint encoding for atomicMax on floats.
// All real floats encode to > 0x007FFFFF, so 0u is a safe "empty" sentinel.
__device__ __forceinline__ unsigned enc_f(float f) {
    unsigned u = __float_as_uint(f);
    return (u & 0x80000000u) ? ~u : (u | 0x80000000u);
}
__device__ __forceinline__ float dec_f(unsigned u) {
    return (u & 0x80000000u) ? __uint_as_float(u ^ 0x80000000u)
                             : __uint_as_float(~u);
}

// K1: xm[n,d] = sum_k x[n,k] * W_msg[k,d] + b_msg[d] + b_edge[d]
__global__ __launch_bounds__(256) void k_xm(const float* __restrict__ x,
                                            const float* __restrict__ W,
                                            const float* __restrict__ b_msg,
                                            const float* __restrict__ b_edge,
                                            float* __restrict__ xm) {
    __shared__ float Ws[DIM * DIM];
    int tid = threadIdx.x;
    #pragma unroll
    for (int i = tid; i < DIM * DIM; i += 256) Ws[i] = W[i];
    __syncthreads();
    int row = blockIdx.x * 4 + (tid >> 6);
    int d = tid & 63;
    if (row >= N_NODES) return;
    const float* xr = x + row * DIM;
    float sum = b_msg[d] + b_edge[d];
    #pragma unroll
    for (int k = 0; k < DIM; ++k) sum += xr[k] * Ws[k * DIM + d];
    xm[row * DIM + d] = sum;
}

// K2: wave per edge. logits[e] = sum_d leakyrelu(msg)*att; atomicMax m[dst].
__global__ __launch_bounds__(256) void k_logits(const float* __restrict__ xm,
                                                const int* __restrict__ eidx,
                                                const float* __restrict__ eattr,
                                                const float* __restrict__ W_edge,
                                                const float* __restrict__ att,
                                                float* __restrict__ logits,
                                                unsigned* __restrict__ mbuf) {
    int wave = (int)((blockIdx.x * 256u + threadIdx.x) >> 6);
    int lane = threadIdx.x & 63;
    if (wave >= N_EDGES) return;
    int src = eidx[wave];
    int dst = eidx[N_EDGES + wave];
    float ea = eattr[wave];
    float msg = xm[src * DIM + lane] + ea * W_edge[lane];
    float lr = msg > 0.f ? msg : NEG_SLOPE * msg;
    float p = lr * att[lane];
    #pragma unroll
    for (int off = 32; off >= 1; off >>= 1) p += __shfl_xor(p, off, 64);
    if (lane == 0) {
        logits[wave] = p;
        atomicMax(mbuf + dst, enc_f(p));
    }
}

// K3: thread per edge. ex = exp(logit - m[dst]); denom[dst] += ex (atomic).
__global__ __launch_bounds__(256) void k_exp(const int* __restrict__ eidx,
                                             const unsigned* __restrict__ mbuf,
                                             float* __restrict__ logits_ex,
                                             float* __restrict__ denom) {
    int e = blockIdx.x * 256 + threadIdx.x;
    if (e >= N_EDGES) return;
    int dst = eidx[N_EDGES + e];
    float l = logits_ex[e];
    float mm = dec_f(mbuf[dst]);   // dst of a live edge -> always a real value
    float ex = expf(l - mm);
    logits_ex[e] = ex;
    atomicAdd(denom + dst, ex);
}

// K4: wave per edge. weighted = msg * alpha; per-component atomicMax into agg.
__global__ __launch_bounds__(256) void k_agg(const float* __restrict__ xm,
                                             const int* __restrict__ eidx,
                                             const float* __restrict__ eattr,
                                             const float* __restrict__ W_edge,
                                             const float* __restrict__ exb,
                                             const float* __restrict__ denom,
                                             unsigned* __restrict__ agg) {
    int wave = (int)((blockIdx.x * 256u + threadIdx.x) >> 6);
    int lane = threadIdx.x & 63;
    if (wave >= N_EDGES) return;
    int src = eidx[wave];
    int dst = eidx[N_EDGES + wave];
    float ea = eattr[wave];
    float msg = xm[src * DIM + lane] + ea * W_edge[lane];
    float alpha = exb[wave] / (denom[dst] + 1e-16f);
    atomicMax(agg + dst * DIM + lane, enc_f(msg * alpha));
}

// K5: out = decode(agg) (+0 for empty segments) + x
__global__ __launch_bounds__(256) void k_out(const unsigned* __restrict__ agg,
                                             const float* __restrict__ x,
                                             float* __restrict__ out) {
    int i = blockIdx.x * 256 + threadIdx.x;
    if (i >= N_NODES * DIM) return;
    unsigned u = agg[i];
    float v = (u == 0u) ? 0.f : dec_f(u);
    out[i] = v + x[i];
}

extern "C" void kernel_launch(void* const* d_in, const int* in_sizes, int n_in,
                              void* d_out, int out_size, void* d_ws, size_t ws_size,
                              hipStream_t stream) {
    const float* x      = (const float*)d_in[0];
    const int*   eidx   = (const int*)d_in[1];     // [2, E] int32
    const float* eattr  = (const float*)d_in[2];
    const float* W_msg  = (const float*)d_in[3];
    const float* b_msg  = (const float*)d_in[4];
    const float* W_edge = (const float*)d_in[5];   // [1, D]
    const float* b_edge = (const float*)d_in[6];
    const float* att    = (const float*)d_in[7];
    float* out = (float*)d_out;

    // Workspace layout (floats/uints, 4B each):
    //   xm:     N*D          (12.8 MB)
    //   logits: E  (reused as ex)  (3.2 MB)
    //   agg:    N*D (uint)   (12.8 MB)   -- zero-init
    //   mbuf:   N   (uint)   (0.2 MB)    -- zero-init
    //   denom:  N   (float)  (0.2 MB)    -- zero-init
    float*    xm     = (float*)d_ws;
    float*    logits = xm + (size_t)N_NODES * DIM;
    unsigned* agg    = (unsigned*)(logits + N_EDGES);
    unsigned* mbuf   = agg + (size_t)N_NODES * DIM;
    float*    denom  = (float*)(mbuf + N_NODES);

    // zero agg + mbuf + denom in one contiguous memset
    hipMemsetAsync(agg, 0, ((size_t)N_NODES * DIM + 2 * (size_t)N_NODES) * 4,
                   stream);

    k_xm<<<N_NODES / 4, 256, 0, stream>>>(x, W_msg, b_msg, b_edge, xm);
    k_logits<<<N_EDGES / 4, 256, 0, stream>>>(xm, eidx, eattr, W_edge, att,
                                              logits, mbuf);
    k_exp<<<N_EDGES / 256, 256, 0, stream>>>(eidx, mbuf, logits, denom);
    k_agg<<<N_EDGES / 4, 256, 0, stream>>>(xm, eidx, eattr, W_edge, logits,
                                           denom, agg);
    k_out<<<(N_NODES * DIM) / 256, 256, 0, stream>>>(agg, x, out);
}

// Round 2
// 350.601 us; speedup vs baseline: 1.3685x; 1.3685x over previous
//
#include <hip/hip_runtime.h>

#define N_NODES 50000
#define N_EDGES 800000
#define DIM 64
#define NEG_SLOPE 0.2f
#define SCAN_T 1024

// K1: xm[n,d] = sum_k x[n,k] * W_msg[k,d] + b_msg[d] + b_edge[d]
__global__ __launch_bounds__(256) void k_xm(const float* __restrict__ x,
                                            const float* __restrict__ W,
                                            const float* __restrict__ b_msg,
                                            const float* __restrict__ b_edge,
                                            float* __restrict__ xm) {
    __shared__ float Ws[DIM * DIM];
    int tid = threadIdx.x;
    #pragma unroll
    for (int i = tid; i < DIM * DIM; i += 256) Ws[i] = W[i];
    __syncthreads();
    int row = blockIdx.x * 4 + (tid >> 6);   // wave-uniform row
    int d = tid & 63;
    const float* xr = x + (size_t)row * DIM;
    float sum = b_msg[d] + b_edge[d];
    #pragma unroll
    for (int k = 0; k < DIM; ++k) sum += xr[k] * Ws[k * DIM + d];
    xm[(size_t)row * DIM + d] = sum;
}

// K2: histogram of destinations
__global__ __launch_bounds__(256) void k_count(const int* __restrict__ eidx,
                                               unsigned* __restrict__ cnt) {
    int e = blockIdx.x * 256 + threadIdx.x;
    if (e >= N_EDGES) return;
    atomicAdd(cnt + eidx[N_EDGES + e], 1u);
}

// K3: single-block exclusive scan over 50k counters -> off[0..N], off[N]=E
__global__ __launch_bounds__(SCAN_T) void k_scan(const unsigned* __restrict__ cnt,
                                                 unsigned* __restrict__ off) {
    __shared__ unsigned sums[SCAN_T];
    int t = threadIdx.x;
    const int per = (N_NODES + SCAN_T - 1) / SCAN_T;   // 49
    int lo = t * per;
    int hi = lo + per; if (hi > N_NODES) hi = N_NODES;
    unsigned s = 0;
    for (int i = lo; i < hi; ++i) s += cnt[i];
    sums[t] = s;
    __syncthreads();
    for (int d = 1; d < SCAN_T; d <<= 1) {        // Hillis-Steele inclusive
        unsigned v = (t >= d) ? sums[t - d] : 0u;
        __syncthreads();
        sums[t] += v;
        __syncthreads();
    }
    unsigned run = sums[t] - s;                    // exclusive prefix of chunk
    for (int i = lo; i < hi; ++i) { off[i] = run; run += cnt[i]; }
    if (t == SCAN_T - 1) off[N_NODES] = sums[t];
}

// K4: scatter edges into CSR order: elist[pos] = {src, bits(edge_attr)}
__global__ __launch_bounds__(256) void k_scatter(const int* __restrict__ eidx,
                                                 const float* __restrict__ eattr,
                                                 const unsigned* __restrict__ off,
                                                 unsigned* __restrict__ cursor,
                                                 int2* __restrict__ elist) {
    int e = blockIdx.x * 256 + threadIdx.x;
    if (e >= N_EDGES) return;
    int dst = eidx[N_EDGES + e];
    unsigned pos = off[dst] + atomicAdd(cursor + dst, 1u);
    elist[pos] = make_int2(eidx[e], __float_as_int(eattr[e]));
}

// K5: wave per destination — fused online-softmax + weighted max + residual.
// Online rescale is exact for max-aggregation: max commutes with the
// uniform positive factor exp(m_old - m_new).
__global__ __launch_bounds__(256) void k_aggregate(const float* __restrict__ xm,
                                                   const int2* __restrict__ elist,
                                                   const unsigned* __restrict__ off,
                                                   const float* __restrict__ W_edge,
                                                   const float* __restrict__ att,
                                                   const float* __restrict__ x,
                                                   float* __restrict__ out) {
    int wave = blockIdx.x * 4 + (threadIdx.x >> 6);
    int lane = threadIdx.x & 63;
    if (wave >= N_NODES) return;
    unsigned beg = off[wave], end = off[wave + 1];
    float we = W_edge[lane], at = att[lane];
    float xv = x[(size_t)wave * DIM + lane];
    if (beg == end) { out[(size_t)wave * DIM + lane] = xv; return; }

    unsigned i = beg;
    int2 e = elist[i];
    float row = xm[(size_t)e.x * DIM + lane];
    float m = 0.f, denom = 0.f, vmax = 0.f;
    bool first = true;
    while (true) {
        bool more = (i + 1 < end);
        int2 en; float rown;
        if (more) {                       // prefetch next edge's row (ILP)
            en = elist[i + 1];
            rown = xm[(size_t)en.x * DIM + lane];
        }
        float ea = __int_as_float(e.y);
        float msg = fmaf(ea, we, row);
        float lr = msg > 0.f ? msg : NEG_SLOPE * msg;
        float p = lr * at;
        #pragma unroll
        for (int o = 32; o >= 1; o >>= 1) p += __shfl_xor(p, o, 64);
        if (first) {
            m = p; denom = 1.f; vmax = msg; first = false;
        } else if (p > m) {               // wave-uniform branch (p,m uniform)
            float s = __expf(m - p);
            denom = fmaf(denom, s, 1.f);
            vmax = fmaxf(vmax * s, msg);
            m = p;
        } else {
            float s = __expf(p - m);
            denom += s;
            vmax = fmaxf(vmax, msg * s);
        }
        if (!more) break;
        e = en; row = rown; ++i;
    }
    out[(size_t)wave * DIM + lane] = vmax / denom + xv;
}

extern "C" void kernel_launch(void* const* d_in, const int* in_sizes, int n_in,
                              void* d_out, int out_size, void* d_ws, size_t ws_size,
                              hipStream_t stream) {
    const float* x      = (const float*)d_in[0];
    const int*   eidx   = (const int*)d_in[1];     // [2, E] int32
    const float* eattr  = (const float*)d_in[2];
    const float* W_msg  = (const float*)d_in[3];
    const float* b_msg  = (const float*)d_in[4];
    const float* W_edge = (const float*)d_in[5];   // [1, D]
    const float* b_edge = (const float*)d_in[6];
    const float* att    = (const float*)d_in[7];
    float* out = (float*)d_out;

    // Workspace layout (u32 units):
    //   xm:     N*DIM        (12.8 MB)
    //   elist:  E*2          (6.4 MB, int2 — 8B-aligned: starts at byte 12.8M)
    //   cnt:    N   \ zeroed together (one 400 KB memset)
    //   cursor: N   /
    //   off:    N+1
    float*    xm     = (float*)d_ws;
    int2*     elist  = (int2*)(xm + (size_t)N_NODES * DIM);
    unsigned* cnt    = (unsigned*)(elist + N_EDGES);
    unsigned* cursor = cnt + N_NODES;
    unsigned* off    = cursor + N_NODES;

    hipMemsetAsync(cnt, 0, 2 * (size_t)N_NODES * 4, stream);

    k_xm<<<N_NODES / 4, 256, 0, stream>>>(x, W_msg, b_msg, b_edge, xm);
    k_count<<<(N_EDGES + 255) / 256, 256, 0, stream>>>(eidx, cnt);
    k_scan<<<1, SCAN_T, 0, stream>>>(cnt, off);
    k_scatter<<<(N_EDGES + 255) / 256, 256, 0, stream>>>(eidx, eattr, off,
                                                         cursor, elist);
    k_aggregate<<<(N_NODES + 3) / 4, 256, 0, stream>>>(xm, elist, off, W_edge,
                                                       att, x, out);
}

// Round 3
// 263.276 us; speedup vs baseline: 1.8224x; 1.3317x over previous
//
#include <hip/hip_runtime.h>

#define N_NODES 50000
#define N_EDGES 800000
#define DIM 64
#define NEG_SLOPE 0.2f
#define SCAN_T 1024
#define NEG_INF (-__builtin_inff())

// K1: xm[n,d] = sum_k x[n,k] * W_msg[k,d] + b_msg[d] + b_edge[d]
// Block = 256 threads = 4 waves; block handles 16 rows (wave w -> rows 4w..4w+3,
// lane d computes column d for those 4 rows). x rows staged in LDS.
__global__ __launch_bounds__(256) void k_xm(const float* __restrict__ x,
                                            const float* __restrict__ W,
                                            const float* __restrict__ b_msg,
                                            const float* __restrict__ b_edge,
                                            float* __restrict__ xm) {
    __shared__ float Ws[DIM * DIM];   // 16 KB
    __shared__ float xs[16 * DIM];    // 4 KB
    int tid = threadIdx.x;
    int base = blockIdx.x * 16;       // N_NODES = 3125 * 16 exactly
    const float4* W4 = (const float4*)W;
    float4* Ws4 = (float4*)Ws;
    #pragma unroll
    for (int i = 0; i < 4; ++i) Ws4[tid + 256 * i] = W4[tid + 256 * i];
    // 16 rows * 64 floats = 256 float4
    ((float4*)xs)[tid] = ((const float4*)(x + (size_t)base * DIM))[tid];
    __syncthreads();

    int w = tid >> 6;        // wave -> rows base + 4w .. +3
    int d = tid & 63;
    float bias = b_msg[d] + b_edge[d];
    float s0 = bias, s1 = bias, s2 = bias, s3 = bias;
    const float* xr = xs + (w * 4) * DIM;
    #pragma unroll
    for (int k = 0; k < DIM; ++k) {
        float wv = Ws[k * DIM + d];
        s0 = fmaf(xr[k], wv, s0);
        s1 = fmaf(xr[DIM + k], wv, s1);
        s2 = fmaf(xr[2 * DIM + k], wv, s2);
        s3 = fmaf(xr[3 * DIM + k], wv, s3);
    }
    float* o = xm + ((size_t)base + w * 4) * DIM + d;
    o[0] = s0; o[DIM] = s1; o[2 * DIM] = s2; o[3 * DIM] = s3;
}

// K2: histogram of destinations + per-edge rank within its destination
__global__ __launch_bounds__(256) void k_count(const int* __restrict__ eidx,
                                               unsigned* __restrict__ cnt,
                                               unsigned short* __restrict__ rank) {
    int e = blockIdx.x * 256 + threadIdx.x;
    if (e >= N_EDGES) return;
    rank[e] = (unsigned short)atomicAdd(cnt + eidx[N_EDGES + e], 1u);
}

// K3: single-block exclusive scan over 50k counters -> off[0..N]
__global__ __launch_bounds__(SCAN_T) void k_scan(const unsigned* __restrict__ cnt,
                                                 unsigned* __restrict__ off) {
    __shared__ unsigned sums[SCAN_T];
    int t = threadIdx.x;
    const int per = (N_NODES + SCAN_T - 1) / SCAN_T;   // 49
    int lo = t * per;
    int hi = lo + per; if (hi > N_NODES) hi = N_NODES;
    unsigned s = 0;
    for (int i = lo; i < hi; ++i) s += cnt[i];
    sums[t] = s;
    __syncthreads();
    for (int d = 1; d < SCAN_T; d <<= 1) {        // Hillis-Steele inclusive
        unsigned v = (t >= d) ? sums[t - d] : 0u;
        __syncthreads();
        sums[t] += v;
        __syncthreads();
    }
    unsigned run = sums[t] - s;                    // exclusive prefix of chunk
    for (int i = lo; i < hi; ++i) { off[i] = run; run += cnt[i]; }
    if (t == SCAN_T - 1) off[N_NODES] = sums[t];
}

// K4: scatter edges into CSR order (no atomics): elist[off[dst]+rank] = {src, ea}
__global__ __launch_bounds__(256) void k_scatter(const int* __restrict__ eidx,
                                                 const float* __restrict__ eattr,
                                                 const unsigned* __restrict__ off,
                                                 const unsigned short* __restrict__ rank,
                                                 int2* __restrict__ elist) {
    int e = blockIdx.x * 256 + threadIdx.x;
    if (e >= N_EDGES) return;
    int dst = eidx[N_EDGES + e];
    unsigned pos = off[dst] + rank[e];
    elist[pos] = make_int2(eidx[e], __float_as_int(eattr[e]));
}

// K5: wave per destination, 4 edges per iteration.
// Lane = 16*g + t: group g handles edge it+g; lane t holds components 4t..4t+3
// (float4). Online softmax + weighted-max, batched over the 4 concurrent edges:
// exact because the rescale factor exp(m_old - M) is uniform and positive.
__global__ __launch_bounds__(256) void k_aggregate(const float4* __restrict__ xm4,
                                                   const int2* __restrict__ elist,
                                                   const unsigned* __restrict__ off,
                                                   const float4* __restrict__ W_edge4,
                                                   const float4* __restrict__ att4,
                                                   const float4* __restrict__ x4,
                                                   float4* __restrict__ out4) {
    int node = blockIdx.x * 4 + (threadIdx.x >> 6);
    int lane = threadIdx.x & 63;
    int g = lane >> 4, t = lane & 15;
    if (node >= N_NODES) return;
    unsigned beg = off[node], end = off[node + 1];
    float4 xv = x4[(size_t)node * 16 + t];
    if (beg == end) {
        if (g == 0) out4[(size_t)node * 16 + t] = xv;
        return;
    }
    float4 we = W_edge4[t], at = att4[t];

    // software-pipelined load of (edge, row)
    unsigned idx = beg + (unsigned)g;
    bool act = idx < end;
    int2 e = elist[act ? idx : beg];
    float4 row = xm4[(size_t)e.x * 16 + t];

    float m = 0.f, denom = 0.f;
    float4 vmax;
    bool first = true;
    for (unsigned it = beg; it < end; it += 4) {
        bool more = (it + 4) < end;          // wave-uniform
        int2 e2; float4 row2; bool act2 = false;
        if (more) {
            unsigned idx2 = it + 4 + (unsigned)g;
            act2 = idx2 < end;
            e2 = elist[act2 ? idx2 : beg];
            row2 = xm4[(size_t)e2.x * 16 + t];
        }
        float ea = __int_as_float(e.y);
        float4 msg;
        msg.x = fmaf(ea, we.x, row.x);
        msg.y = fmaf(ea, we.y, row.y);
        msg.z = fmaf(ea, we.z, row.z);
        msg.w = fmaf(ea, we.w, row.w);
        float lx = msg.x > 0.f ? msg.x : NEG_SLOPE * msg.x;
        float ly = msg.y > 0.f ? msg.y : NEG_SLOPE * msg.y;
        float lz = msg.z > 0.f ? msg.z : NEG_SLOPE * msg.z;
        float lw = msg.w > 0.f ? msg.w : NEG_SLOPE * msg.w;
        float p = fmaf(lx, at.x, fmaf(ly, at.y, fmaf(lz, at.z, lw * at.w)));
        // reduce within the 16-lane group (p becomes group-uniform)
        p += __shfl_xor(p, 1, 64);
        p += __shfl_xor(p, 2, 64);
        p += __shfl_xor(p, 4, 64);
        p += __shfl_xor(p, 8, 64);
        p = act ? p : NEG_INF;
        // batch max across the 4 groups
        float pm = fmaxf(p, __shfl_xor(p, 16, 64));
        pm = fmaxf(pm, __shfl_xor(pm, 32, 64));
        float M = first ? pm : fmaxf(m, pm);
        float sc = __expf(p - M);            // 0 for inactive groups
        // batch sum of exps across groups
        float es = sc + __shfl_xor(sc, 16, 64);
        es += __shfl_xor(es, 32, 64);
        // per-component scaled contribution, max across groups
        float4 c;
        c.x = act ? msg.x * sc : NEG_INF;
        c.y = act ? msg.y * sc : NEG_INF;
        c.z = act ? msg.z * sc : NEG_INF;
        c.w = act ? msg.w * sc : NEG_INF;
        c.x = fmaxf(c.x, __shfl_xor(c.x, 16, 64));
        c.y = fmaxf(c.y, __shfl_xor(c.y, 16, 64));
        c.z = fmaxf(c.z, __shfl_xor(c.z, 16, 64));
        c.w = fmaxf(c.w, __shfl_xor(c.w, 16, 64));
        c.x = fmaxf(c.x, __shfl_xor(c.x, 32, 64));
        c.y = fmaxf(c.y, __shfl_xor(c.y, 32, 64));
        c.z = fmaxf(c.z, __shfl_xor(c.z, 32, 64));
        c.w = fmaxf(c.w, __shfl_xor(c.w, 32, 64));
        if (first) {
            m = M; denom = es; vmax = c; first = false;
        } else {
            float so = __expf(m - M);
            denom = fmaf(denom, so, es);
            vmax.x = fmaxf(vmax.x * so, c.x);
            vmax.y = fmaxf(vmax.y * so, c.y);
            vmax.z = fmaxf(vmax.z * so, c.z);
            vmax.w = fmaxf(vmax.w * so, c.w);
            m = M;
        }
        e = e2; row = row2; act = act2;
    }
    float inv = 1.0f / (denom + 1e-16f);
    if (g == 0) {
        float4 r;
        r.x = fmaf(vmax.x, inv, xv.x);
        r.y = fmaf(vmax.y, inv, xv.y);
        r.z = fmaf(vmax.z, inv, xv.z);
        r.w = fmaf(vmax.w, inv, xv.w);
        out4[(size_t)node * 16 + t] = r;
    }
}

extern "C" void kernel_launch(void* const* d_in, const int* in_sizes, int n_in,
                              void* d_out, int out_size, void* d_ws, size_t ws_size,
                              hipStream_t stream) {
    const float* x      = (const float*)d_in[0];
    const int*   eidx   = (const int*)d_in[1];     // [2, E] int32
    const float* eattr  = (const float*)d_in[2];
    const float* W_msg  = (const float*)d_in[3];
    const float* b_msg  = (const float*)d_in[4];
    const float* W_edge = (const float*)d_in[5];   // [1, D]
    const float* b_edge = (const float*)d_in[6];
    const float* att    = (const float*)d_in[7];
    float* out = (float*)d_out;

    // Workspace layout (bytes):
    //   xm:    N*64 f32   12.8 MB
    //   elist: E int2      6.4 MB
    //   cnt:   N u32       0.2 MB   -- zeroed
    //   off:   N+1 u32
    //   rank:  E u16       1.6 MB
    float*          xm    = (float*)d_ws;
    int2*           elist = (int2*)(xm + (size_t)N_NODES * DIM);
    unsigned*       cnt   = (unsigned*)(elist + N_EDGES);
    unsigned*       off   = cnt + N_NODES;
    unsigned short* rank  = (unsigned short*)(off + N_NODES + 1);

    hipMemsetAsync(cnt, 0, (size_t)N_NODES * 4, stream);

    k_xm<<<N_NODES / 16, 256, 0, stream>>>(x, W_msg, b_msg, b_edge, xm);
    k_count<<<N_EDGES / 256, 256, 0, stream>>>(eidx, cnt, rank);
    k_scan<<<1, SCAN_T, 0, stream>>>(cnt, off);
    k_scatter<<<N_EDGES / 256, 256, 0, stream>>>(eidx, eattr, off, rank, elist);
    k_aggregate<<<(N_NODES + 3) / 4, 256, 0, stream>>>(
        (const float4*)xm, elist, off, (const float4*)W_edge,
        (const float4*)att, (const float4*)x, (float4*)out);
}

// Round 4
// 191.816 us; speedup vs baseline: 2.5013x; 1.3725x over previous
//
#include <hip/hip_runtime.h>

#define N_NODES 50000
#define N_EDGES 800000
#define DIM 64
#define NEG_SLOPE 0.2f
#define NEG_INF (-__builtin_inff())
#define SCAN_NB 196          // ceil(50000/256)

// K1: xm[n,d] = sum_k x[n,k] * W_msg[k,d] + b_msg[d] + b_edge[d]
__global__ __launch_bounds__(256) void k_xm(const float* __restrict__ x,
                                            const float* __restrict__ W,
                                            const float* __restrict__ b_msg,
                                            const float* __restrict__ b_edge,
                                            float* __restrict__ xm) {
    __shared__ float Ws[DIM * DIM];   // 16 KB
    __shared__ float xs[16 * DIM];    // 4 KB
    int tid = threadIdx.x;
    int base = blockIdx.x * 16;       // N_NODES = 3125 * 16 exactly
    const float4* W4 = (const float4*)W;
    float4* Ws4 = (float4*)Ws;
    #pragma unroll
    for (int i = 0; i < 4; ++i) Ws4[tid + 256 * i] = W4[tid + 256 * i];
    ((float4*)xs)[tid] = ((const float4*)(x + (size_t)base * DIM))[tid];
    __syncthreads();

    int w = tid >> 6;
    int d = tid & 63;
    float bias = b_msg[d] + b_edge[d];
    float s0 = bias, s1 = bias, s2 = bias, s3 = bias;
    const float* xr = xs + (w * 4) * DIM;
    #pragma unroll
    for (int k = 0; k < DIM; ++k) {
        float wv = Ws[k * DIM + d];
        s0 = fmaf(xr[k], wv, s0);
        s1 = fmaf(xr[DIM + k], wv, s1);
        s2 = fmaf(xr[2 * DIM + k], wv, s2);
        s3 = fmaf(xr[3 * DIM + k], wv, s3);
    }
    float* o = xm + ((size_t)base + w * 4) * DIM + d;
    o[0] = s0; o[DIM] = s1; o[2 * DIM] = s2; o[3 * DIM] = s3;
}

// K2: histogram of destinations + per-edge rank within its destination
__global__ __launch_bounds__(256) void k_count(const int* __restrict__ eidx,
                                               unsigned* __restrict__ cnt,
                                               unsigned short* __restrict__ rank) {
    int e = blockIdx.x * 256 + threadIdx.x;
    if (e >= N_EDGES) return;
    rank[e] = (unsigned short)atomicAdd(cnt + eidx[N_EDGES + e], 1u);
}

// K3a: per-block (256-chunk) sums of cnt -> partial[SCAN_NB]
__global__ __launch_bounds__(256) void k_scan1(const unsigned* __restrict__ cnt,
                                               unsigned* __restrict__ partial) {
    int t = threadIdx.x;
    int i = blockIdx.x * 256 + t;
    unsigned v = (i < N_NODES) ? cnt[i] : 0u;
    #pragma unroll
    for (int o = 32; o >= 1; o >>= 1) v += __shfl_xor(v, o, 64);
    __shared__ unsigned ws[4];
    if ((t & 63) == 0) ws[t >> 6] = v;
    __syncthreads();
    if (t == 0) partial[blockIdx.x] = ws[0] + ws[1] + ws[2] + ws[3];
}

// K3b: single block — exclusive scan of SCAN_NB partials -> bases; off[N]=E
__global__ __launch_bounds__(256) void k_scan2(unsigned* __restrict__ partial,
                                               unsigned* __restrict__ off) {
    int t = threadIdx.x;
    int lane = t & 63, w = t >> 6;
    unsigned v = (t < SCAN_NB) ? partial[t] : 0u;
    unsigned inc = v;
    #pragma unroll
    for (int d = 1; d < 64; d <<= 1) {
        unsigned u = __shfl_up(inc, d, 64);
        if (lane >= d) inc += u;
    }
    __shared__ unsigned ws[4];
    if (lane == 63) ws[w] = inc;
    __syncthreads();
    unsigned wadd = 0;
    #pragma unroll
    for (int k = 0; k < 4; ++k) if (k < w) wadd += ws[k];
    if (t < SCAN_NB) partial[t] = inc - v + wadd;   // exclusive base
    if (t == 0) off[N_NODES] = N_EDGES;
}

// K3c: per-block exclusive scan of its 256-chunk + base -> off
__global__ __launch_bounds__(256) void k_scan3(const unsigned* __restrict__ cnt,
                                               const unsigned* __restrict__ partial,
                                               unsigned* __restrict__ off) {
    int t = threadIdx.x;
    int lane = t & 63, w = t >> 6;
    int i = blockIdx.x * 256 + t;
    unsigned v = (i < N_NODES) ? cnt[i] : 0u;
    unsigned inc = v;
    #pragma unroll
    for (int d = 1; d < 64; d <<= 1) {
        unsigned u = __shfl_up(inc, d, 64);
        if (lane >= d) inc += u;
    }
    __shared__ unsigned ws[4];
    if (lane == 63) ws[w] = inc;
    __syncthreads();
    unsigned wadd = partial[blockIdx.x];
    #pragma unroll
    for (int k = 0; k < 4; ++k) if (k < w) wadd += ws[k];
    if (i < N_NODES) off[i] = inc - v + wadd;
}

// K4: scatter edges into CSR order (no atomics)
__global__ __launch_bounds__(256) void k_scatter(const int* __restrict__ eidx,
                                                 const float* __restrict__ eattr,
                                                 const unsigned* __restrict__ off,
                                                 const unsigned short* __restrict__ rank,
                                                 int2* __restrict__ elist) {
    int e = blockIdx.x * 256 + threadIdx.x;
    if (e >= N_EDGES) return;
    int dst = eidx[N_EDGES + e];
    unsigned pos = off[dst] + rank[e];
    elist[pos] = make_int2(eidx[e], __float_as_int(eattr[e]));
}

// K5: wave per destination, 4 edges per iteration (16-lane groups x float4).
__global__ __launch_bounds__(256) void k_aggregate(const float4* __restrict__ xm4,
                                                   const int2* __restrict__ elist,
                                                   const unsigned* __restrict__ off,
                                                   const float4* __restrict__ W_edge4,
                                                   const float4* __restrict__ att4,
                                                   const float4* __restrict__ x4,
                                                   float4* __restrict__ out4) {
    int node = blockIdx.x * 4 + (threadIdx.x >> 6);
    int lane = threadIdx.x & 63;
    int g = lane >> 4, t = lane & 15;
    if (node >= N_NODES) return;
    unsigned beg = off[node], end = off[node + 1];
    float4 xv = x4[(size_t)node * 16 + t];
    if (beg == end) {
        if (g == 0) out4[(size_t)node * 16 + t] = xv;
        return;
    }
    float4 we = W_edge4[t], at = att4[t];

    unsigned idx = beg + (unsigned)g;
    bool act = idx < end;
    int2 e = elist[act ? idx : beg];
    float4 row = xm4[(size_t)e.x * 16 + t];

    float m = 0.f, denom = 0.f;
    float4 vmax;
    bool first = true;
    for (unsigned it = beg; it < end; it += 4) {
        bool more = (it + 4) < end;          // wave-uniform
        int2 e2; float4 row2; bool act2 = false;
        if (more) {
            unsigned idx2 = it + 4 + (unsigned)g;
            act2 = idx2 < end;
            e2 = elist[act2 ? idx2 : beg];
            row2 = xm4[(size_t)e2.x * 16 + t];
        }
        float ea = __int_as_float(e.y);
        float4 msg;
        msg.x = fmaf(ea, we.x, row.x);
        msg.y = fmaf(ea, we.y, row.y);
        msg.z = fmaf(ea, we.z, row.z);
        msg.w = fmaf(ea, we.w, row.w);
        float lx = msg.x > 0.f ? msg.x : NEG_SLOPE * msg.x;
        float ly = msg.y > 0.f ? msg.y : NEG_SLOPE * msg.y;
        float lz = msg.z > 0.f ? msg.z : NEG_SLOPE * msg.z;
        float lw = msg.w > 0.f ? msg.w : NEG_SLOPE * msg.w;
        float p = fmaf(lx, at.x, fmaf(ly, at.y, fmaf(lz, at.z, lw * at.w)));
        p += __shfl_xor(p, 1, 64);
        p += __shfl_xor(p, 2, 64);
        p += __shfl_xor(p, 4, 64);
        p += __shfl_xor(p, 8, 64);
        p = act ? p : NEG_INF;
        float pm = fmaxf(p, __shfl_xor(p, 16, 64));
        pm = fmaxf(pm, __shfl_xor(pm, 32, 64));
        float M = first ? pm : fmaxf(m, pm);
        float sc = __expf(p - M);
        float es = sc + __shfl_xor(sc, 16, 64);
        es += __shfl_xor(es, 32, 64);
        float4 c;
        c.x = act ? msg.x * sc : NEG_INF;
        c.y = act ? msg.y * sc : NEG_INF;
        c.z = act ? msg.z * sc : NEG_INF;
        c.w = act ? msg.w * sc : NEG_INF;
        c.x = fmaxf(c.x, __shfl_xor(c.x, 16, 64));
        c.y = fmaxf(c.y, __shfl_xor(c.y, 16, 64));
        c.z = fmaxf(c.z, __shfl_xor(c.z, 16, 64));
        c.w = fmaxf(c.w, __shfl_xor(c.w, 16, 64));
        c.x = fmaxf(c.x, __shfl_xor(c.x, 32, 64));
        c.y = fmaxf(c.y, __shfl_xor(c.y, 32, 64));
        c.z = fmaxf(c.z, __shfl_xor(c.z, 32, 64));
        c.w = fmaxf(c.w, __shfl_xor(c.w, 32, 64));
        if (first) {
            m = M; denom = es; vmax = c; first = false;
        } else {
            float so = __expf(m - M);
            denom = fmaf(denom, so, es);
            vmax.x = fmaxf(vmax.x * so, c.x);
            vmax.y = fmaxf(vmax.y * so, c.y);
            vmax.z = fmaxf(vmax.z * so, c.z);
            vmax.w = fmaxf(vmax.w * so, c.w);
            m = M;
        }
        e = e2; row = row2; act = act2;
    }
    float inv = 1.0f / (denom + 1e-16f);
    if (g == 0) {
        float4 r;
        r.x = fmaf(vmax.x, inv, xv.x);
        r.y = fmaf(vmax.y, inv, xv.y);
        r.z = fmaf(vmax.z, inv, xv.z);
        r.w = fmaf(vmax.w, inv, xv.w);
        out4[(size_t)node * 16 + t] = r;
    }
}

extern "C" void kernel_launch(void* const* d_in, const int* in_sizes, int n_in,
                              void* d_out, int out_size, void* d_ws, size_t ws_size,
                              hipStream_t stream) {
    const float* x      = (const float*)d_in[0];
    const int*   eidx   = (const int*)d_in[1];     // [2, E] int32
    const float* eattr  = (const float*)d_in[2];
    const float* W_msg  = (const float*)d_in[3];
    const float* b_msg  = (const float*)d_in[4];
    const float* W_edge = (const float*)d_in[5];   // [1, D]
    const float* b_edge = (const float*)d_in[6];
    const float* att    = (const float*)d_in[7];
    float* out = (float*)d_out;

    // Workspace layout:
    //   xm:      N*64 f32   12.8 MB
    //   elist:   E int2      6.4 MB
    //   cnt:     N u32       0.2 MB   -- zeroed
    //   off:     N+1 u32
    //   partial: SCAN_NB u32
    //   rank:    E u16       1.6 MB
    float*          xm      = (float*)d_ws;
    int2*           elist   = (int2*)(xm + (size_t)N_NODES * DIM);
    unsigned*       cnt     = (unsigned*)(elist + N_EDGES);
    unsigned*       off     = cnt + N_NODES;
    unsigned*       partial = off + N_NODES + 1;
    unsigned short* rank    = (unsigned short*)(partial + SCAN_NB);

    hipMemsetAsync(cnt, 0, (size_t)N_NODES * 4, stream);

    k_xm<<<N_NODES / 16, 256, 0, stream>>>(x, W_msg, b_msg, b_edge, xm);
    k_count<<<N_EDGES / 256, 256, 0, stream>>>(eidx, cnt, rank);
    k_scan1<<<SCAN_NB, 256, 0, stream>>>(cnt, partial);
    k_scan2<<<1, 256, 0, stream>>>(partial, off);
    k_scan3<<<SCAN_NB, 256, 0, stream>>>(cnt, partial, off);
    k_scatter<<<N_EDGES / 256, 256, 0, stream>>>(eidx, eattr, off, rank, elist);
    k_aggregate<<<(N_NODES + 3) / 4, 256, 0, stream>>>(
        (const float4*)xm, elist, off, (const float4*)W_edge,
        (const float4*)att, (const float4*)x, (float4*)out);
}

// Round 5
// 171.678 us; speedup vs baseline: 2.7947x; 1.1173x over previous
//
#include <hip/hip_runtime.h>

#define N_NODES 50000
#define N_EDGES 800000
#define DIM 64
#define NEG_SLOPE 0.2f
#define NEG_INF (-__builtin_inff())
#define SCAN_NB 196          // ceil(50000/256)
#define XM_NB   3125         // N_NODES/16
#define CNT_NB  782          // ceil(800000/1024)

typedef _Float16 half8 __attribute__((ext_vector_type(8)));

// K1 (fused): blocks [0,XM_NB) compute xm fp16 = x@W + b_msg + b_edge;
// blocks [XM_NB, XM_NB+CNT_NB) do the dst histogram + per-edge rank.
__global__ __launch_bounds__(256) void k_pre(const float* __restrict__ x,
                                             const float* __restrict__ W,
                                             const float* __restrict__ b_msg,
                                             const float* __restrict__ b_edge,
                                             _Float16* __restrict__ xmh,
                                             const int* __restrict__ eidx,
                                             unsigned* __restrict__ cnt,
                                             unsigned short* __restrict__ rank) {
    __shared__ float Ws[DIM * DIM];   // 16 KB
    __shared__ float xs[16 * DIM];    // 4 KB
    int tid = threadIdx.x;
    if (blockIdx.x >= XM_NB) {        // ---- histogram part ----
        int e0 = (blockIdx.x - XM_NB) * 1024 + tid;
        #pragma unroll
        for (int j = 0; j < 4; ++j) {
            int e = e0 + j * 256;
            if (e < N_EDGES)
                rank[e] = (unsigned short)atomicAdd(cnt + eidx[N_EDGES + e], 1u);
        }
        return;
    }
    // ---- xm part ----
    int base = blockIdx.x * 16;
    const float4* W4 = (const float4*)W;
    float4* Ws4 = (float4*)Ws;
    #pragma unroll
    for (int i = 0; i < 4; ++i) Ws4[tid + 256 * i] = W4[tid + 256 * i];
    ((float4*)xs)[tid] = ((const float4*)(x + (size_t)base * DIM))[tid];
    __syncthreads();

    int w = tid >> 6;
    int d = tid & 63;
    float bias = b_msg[d] + b_edge[d];
    float s0 = bias, s1 = bias, s2 = bias, s3 = bias;
    const float* xr = xs + (w * 4) * DIM;
    #pragma unroll
    for (int k = 0; k < DIM; ++k) {
        float wv = Ws[k * DIM + d];
        s0 = fmaf(xr[k], wv, s0);
        s1 = fmaf(xr[DIM + k], wv, s1);
        s2 = fmaf(xr[2 * DIM + k], wv, s2);
        s3 = fmaf(xr[3 * DIM + k], wv, s3);
    }
    _Float16* o = xmh + ((size_t)base + w * 4) * DIM + d;
    o[0] = (_Float16)s0;
    o[DIM] = (_Float16)s1;
    o[2 * DIM] = (_Float16)s2;
    o[3 * DIM] = (_Float16)s3;
}

// K2a: per-block (256-chunk) sums of cnt -> partial[SCAN_NB]
__global__ __launch_bounds__(256) void k_scan1(const unsigned* __restrict__ cnt,
                                               unsigned* __restrict__ partial) {
    int t = threadIdx.x;
    int i = blockIdx.x * 256 + t;
    unsigned v = (i < N_NODES) ? cnt[i] : 0u;
    #pragma unroll
    for (int o = 32; o >= 1; o >>= 1) v += __shfl_xor(v, o, 64);
    __shared__ unsigned ws[4];
    if ((t & 63) == 0) ws[t >> 6] = v;
    __syncthreads();
    if (t == 0) partial[blockIdx.x] = ws[0] + ws[1] + ws[2] + ws[3];
}

// K2b: each block redundantly scans all 196 partials (784 B), then scans its
// own 256-chunk and writes off. Replaces the separate scan2+scan3.
__global__ __launch_bounds__(256) void k_scan23(const unsigned* __restrict__ cnt,
                                                const unsigned* __restrict__ partial,
                                                unsigned* __restrict__ off) {
    int t = threadIdx.x;
    int lane = t & 63, w = t >> 6;
    __shared__ unsigned ws[4];
    __shared__ unsigned baseLds;
    // phase A: exclusive scan of partial[], keep entry blockIdx.x
    unsigned pv = (t < SCAN_NB) ? partial[t] : 0u;
    unsigned inc = pv;
    #pragma unroll
    for (int d = 1; d < 64; d <<= 1) {
        unsigned u = __shfl_up(inc, d, 64);
        if (lane >= d) inc += u;
    }
    if (lane == 63) ws[w] = inc;
    __syncthreads();
    unsigned wadd = 0;
    #pragma unroll
    for (int k = 0; k < 4; ++k) if (k < w) wadd += ws[k];
    if (t == (int)blockIdx.x) baseLds = inc - pv + wadd;
    __syncthreads();
    unsigned base = baseLds;
    // phase B: scan own chunk
    int i = blockIdx.x * 256 + t;
    unsigned v = (i < N_NODES) ? cnt[i] : 0u;
    unsigned inc2 = v;
    #pragma unroll
    for (int d = 1; d < 64; d <<= 1) {
        unsigned u = __shfl_up(inc2, d, 64);
        if (lane >= d) inc2 += u;
    }
    if (lane == 63) ws[w] = inc2;
    __syncthreads();
    unsigned wadd2 = 0;
    #pragma unroll
    for (int k = 0; k < 4; ++k) if (k < w) wadd2 += ws[k];
    if (i < N_NODES) off[i] = inc2 - v + wadd2 + base;
    if (blockIdx.x == 0 && t == 0) off[N_NODES] = N_EDGES;
}

// K3: scatter edges into CSR order (no atomics)
__global__ __launch_bounds__(256) void k_scatter(const int* __restrict__ eidx,
                                                 const float* __restrict__ eattr,
                                                 const unsigned* __restrict__ off,
                                                 const unsigned short* __restrict__ rank,
                                                 int2* __restrict__ elist) {
    int e = blockIdx.x * 256 + threadIdx.x;
    if (e >= N_EDGES) return;
    int dst = eidx[N_EDGES + e];
    unsigned pos = off[dst] + rank[e];
    elist[pos] = make_int2(eidx[e], __float_as_int(eattr[e]));
}

// K4: wave per destination; 8 groups x 8 lanes; 8 edges per iteration.
// Each group keeps an independent online-softmax state (m, denom, vmax) over
// its strided 1/8 of the edge list; states are merged once at the end.
// Exact: max-aggregation commutes with the uniform positive rescale.
__global__ __launch_bounds__(256) void k_aggregate(const half8* __restrict__ xm8,
                                                   const int2* __restrict__ elist,
                                                   const unsigned* __restrict__ off,
                                                   const float4* __restrict__ W_edge4,
                                                   const float4* __restrict__ att4,
                                                   const float4* __restrict__ x4,
                                                   float4* __restrict__ out4) {
    int node = blockIdx.x * 4 + (threadIdx.x >> 6);
    int lane = threadIdx.x & 63;
    int g = lane >> 3, t = lane & 7;
    unsigned beg = off[node], end = off[node + 1];
    size_t obase = (size_t)node * 16 + 2 * t;
    if (beg == end) {
        if (g == 0) { out4[obase] = x4[obase]; out4[obase + 1] = x4[obase + 1]; }
        return;
    }
    float4 wa = W_edge4[2 * t], wb = W_edge4[2 * t + 1];
    float4 aa = att4[2 * t],    ab = att4[2 * t + 1];
    float we[8] = {wa.x, wa.y, wa.z, wa.w, wb.x, wb.y, wb.z, wb.w};
    float at[8] = {aa.x, aa.y, aa.z, aa.w, ab.x, ab.y, ab.z, ab.w};

    unsigned idx = beg + (unsigned)g;
    bool act = idx < end;
    int2 e = elist[act ? idx : beg];
    half8 h = xm8[(size_t)e.x * 8 + t];

    float m = NEG_INF, denom = 0.f;
    float v[8];
    #pragma unroll
    for (int k = 0; k < 8; ++k) v[k] = 0.f;
    bool first = true;

    for (unsigned b = beg;; b += 8) {
        bool more = (b + 8) < end;         // wave-uniform
        int2 e2; half8 h2; bool a2 = false;
        if (more) {                        // prefetch next 8 edges
            unsigned i2 = b + 8 + (unsigned)g;
            a2 = i2 < end;
            e2 = elist[a2 ? i2 : beg];
            h2 = xm8[(size_t)e2.x * 8 + t];
        }
        float ea = __int_as_float(e.y);
        float msg[8];
        float p = 0.f;
        #pragma unroll
        for (int k = 0; k < 8; ++k) {
            float f = (float)h[k];
            msg[k] = fmaf(ea, we[k], f);
            float lr = fmaxf(msg[k], NEG_SLOPE * msg[k]);   // leaky (slope<1)
            p = fmaf(lr, at[k], p);
        }
        p += __shfl_xor(p, 1, 64);
        p += __shfl_xor(p, 2, 64);
        p += __shfl_xor(p, 4, 64);          // group-uniform logit
        if (first) {
            if (act) {
                m = p; denom = 1.f;
                #pragma unroll
                for (int k = 0; k < 8; ++k) v[k] = msg[k];
            }
            first = false;
        } else if (act) {
            float M = fmaxf(m, p);
            float so = __expf(m - M);
            float sn = __expf(p - M);
            denom = fmaf(denom, so, sn);
            #pragma unroll
            for (int k = 0; k < 8; ++k)
                v[k] = fmaxf(v[k] * so, msg[k] * sn);
            m = M;
        }
        if (!more) break;
        e = e2; h = h2; act = a2;
    }
    // merge the 8 per-group states
    bool has = denom > 0.f;
    float Ms = m;                           // NEG_INF when !has
    Ms = fmaxf(Ms, __shfl_xor(Ms, 8, 64));
    Ms = fmaxf(Ms, __shfl_xor(Ms, 16, 64));
    Ms = fmaxf(Ms, __shfl_xor(Ms, 32, 64));
    float s = has ? __expf(m - Ms) : 0.f;
    float dd = denom * s;
    dd += __shfl_xor(dd, 8, 64);
    dd += __shfl_xor(dd, 16, 64);
    dd += __shfl_xor(dd, 32, 64);
    float gv[8];
    #pragma unroll
    for (int k = 0; k < 8; ++k) {
        float gk = has ? v[k] * s : NEG_INF;
        gk = fmaxf(gk, __shfl_xor(gk, 8, 64));
        gk = fmaxf(gk, __shfl_xor(gk, 16, 64));
        gk = fmaxf(gk, __shfl_xor(gk, 32, 64));
        gv[k] = gk;
    }
    if (g == 0) {
        float inv = 1.0f / (dd + 1e-16f);
        float4 xa = x4[obase], xb = x4[obase + 1];
        float4 r0, r1;
        r0.x = fmaf(gv[0], inv, xa.x);
        r0.y = fmaf(gv[1], inv, xa.y);
        r0.z = fmaf(gv[2], inv, xa.z);
        r0.w = fmaf(gv[3], inv, xa.w);
        r1.x = fmaf(gv[4], inv, xb.x);
        r1.y = fmaf(gv[5], inv, xb.y);
        r1.z = fmaf(gv[6], inv, xb.z);
        r1.w = fmaf(gv[7], inv, xb.w);
        out4[obase] = r0;
        out4[obase + 1] = r1;
    }
}

extern "C" void kernel_launch(void* const* d_in, const int* in_sizes, int n_in,
                              void* d_out, int out_size, void* d_ws, size_t ws_size,
                              hipStream_t stream) {
    const float* x      = (const float*)d_in[0];
    const int*   eidx   = (const int*)d_in[1];     // [2, E] int32
    const float* eattr  = (const float*)d_in[2];
    const float* W_msg  = (const float*)d_in[3];
    const float* b_msg  = (const float*)d_in[4];
    const float* W_edge = (const float*)d_in[5];   // [1, D]
    const float* b_edge = (const float*)d_in[6];
    const float* att    = (const float*)d_in[7];
    float* out = (float*)d_out;

    // Workspace layout:
    //   xmh:     N*64 fp16   6.4 MB
    //   elist:   E int2      6.4 MB
    //   cnt:     N u32       0.2 MB   -- zeroed
    //   off:     N+1 u32
    //   partial: SCAN_NB u32
    //   rank:    E u16       1.6 MB
    _Float16*       xmh     = (_Float16*)d_ws;
    int2*           elist   = (int2*)(xmh + (size_t)N_NODES * DIM);
    unsigned*       cnt     = (unsigned*)(elist + N_EDGES);
    unsigned*       off     = cnt + N_NODES;
    unsigned*       partial = off + N_NODES + 1;
    unsigned short* rank    = (unsigned short*)(partial + SCAN_NB);

    hipMemsetAsync(cnt, 0, (size_t)N_NODES * 4, stream);

    k_pre<<<XM_NB + CNT_NB, 256, 0, stream>>>(x, W_msg, b_msg, b_edge, xmh,
                                              eidx, cnt, rank);
    k_scan1<<<SCAN_NB, 256, 0, stream>>>(cnt, partial);
    k_scan23<<<SCAN_NB, 256, 0, stream>>>(cnt, partial, off);
    k_scatter<<<N_EDGES / 256, 256, 0, stream>>>(eidx, eattr, off, rank, elist);
    k_aggregate<<<N_NODES / 4, 256, 0, stream>>>(
        (const half8*)xmh, elist, off, (const float4*)W_edge,
        (const float4*)att, (const float4*)x, (float4*)out);
}